// Round 2
// baseline (11.562 us; speedup 1.0000x reference)
//
#include <hip/hip_runtime.h>

// Haar(10 levels, 1023 feats) -> MLP 1023->8->8->3 is piecewise constant on
// the 1024 dyadic leaf intervals [u/1024,(u+1)/1024), u = floor(t*1024):
// every interval edge in the reference is a multiple of 2^-10, so the mask
// vector H depends only on u. Precompute a 1024-entry LUT of the full
// network output (kernel A), then the main pass is a pure lookup (kernel B).
//
// Integer form (exact): level j has k = u >> (10-j),
// sign = +1 if bit (9-j) of u is 0 (left half) else -1; row = 2^j - 1 + k.
// floor(t*1024) is exact in f32: *1024 is a power-of-2 scale, 0 <= t < 1.

__global__ __launch_bounds__(256) void haar_build_lut(
    const float* __restrict__ W1, const float* __restrict__ b1,
    const float* __restrict__ W2, const float* __restrict__ b2,
    const float* __restrict__ W3, const float* __restrict__ b3,
    float4* __restrict__ lut)
{
    int u = blockIdx.x * 256 + (int)threadIdx.x;
    if (u >= 1024) return;

    float h1[8];
    #pragma unroll
    for (int o = 0; o < 8; ++o) h1[o] = b1[o];

    #pragma unroll
    for (int j = 0; j < 10; ++j) {
        int row = (1 << j) - 1 + (u >> (10 - j));
        float sgn = ((u >> (9 - j)) & 1) ? -1.0f : 1.0f;
        const float4* wp = reinterpret_cast<const float4*>(W1 + row * 8);
        float4 lo = wp[0];
        float4 hi = wp[1];
        h1[0] += sgn * lo.x; h1[1] += sgn * lo.y;
        h1[2] += sgn * lo.z; h1[3] += sgn * lo.w;
        h1[4] += sgn * hi.x; h1[5] += sgn * hi.y;
        h1[6] += sgn * hi.z; h1[7] += sgn * hi.w;
    }
    #pragma unroll
    for (int o = 0; o < 8; ++o) h1[o] = fmaxf(h1[o], 0.0f);

    float h2[8];
    #pragma unroll
    for (int o = 0; o < 8; ++o) {
        float a = b2[o];
        #pragma unroll
        for (int q = 0; q < 8; ++q) a = fmaf(h1[q], W2[q * 8 + o], a);
        h2[o] = fmaxf(a, 0.0f);
    }

    float o0 = b3[0], o1 = b3[1], o2 = b3[2];
    #pragma unroll
    for (int q = 0; q < 8; ++q) {
        o0 = fmaf(h2[q], W3[q * 3 + 0], o0);
        o1 = fmaf(h2[q], W3[q * 3 + 1], o1);
        o2 = fmaf(h2[q], W3[q * 3 + 2], o2);
    }
    lut[u] = make_float4(o0, o1, o2, 0.0f);
}

__global__ __launch_bounds__(256) void haar_apply_lut(
    const float* __restrict__ t,
    const float4* __restrict__ lut,
    float* __restrict__ out, int n)
{
    __shared__ float4 l[1024];
    #pragma unroll
    for (int u = 0; u < 4; ++u)
        l[(int)threadIdx.x + u * 256] = lut[(int)threadIdx.x + u * 256];
    __syncthreads();

    int i = blockIdx.x * 256 + (int)threadIdx.x;
    if (i >= n) return;

    float tv = t[i];
    int u = (int)(tv * 1024.0f);
    u = (u < 0) ? 0 : (u > 1023 ? 1023 : u);
    float4 r = l[u];
    out[i * 3 + 0] = r.x;
    out[i * 3 + 1] = r.y;
    out[i * 3 + 2] = r.z;
}

extern "C" void kernel_launch(void* const* d_in, const int* in_sizes, int n_in,
                              void* d_out, int out_size, void* d_ws, size_t ws_size,
                              hipStream_t stream) {
    const float* t  = (const float*)d_in[0];
    const float* W1 = (const float*)d_in[1];
    const float* b1 = (const float*)d_in[2];
    const float* W2 = (const float*)d_in[3];
    const float* b2 = (const float*)d_in[4];
    const float* W3 = (const float*)d_in[5];
    const float* b3 = (const float*)d_in[6];
    float* out = (float*)d_out;
    float4* lut = (float4*)d_ws;  // 16 KiB scratch

    int n = in_sizes[0];  // B*T = 131072
    haar_build_lut<<<4, 256, 0, stream>>>(W1, b1, W2, b2, W3, b3, lut);
    haar_apply_lut<<<(n + 255) / 256, 256, 0, stream>>>(t, lut, out, n);
}